// Round 1
// baseline (220.590 us; speedup 1.0000x reference)
//
#include <hip/hip_runtime.h>

#define BATCH 32
#define SEQ   1024
#define DH    64

typedef short s16x4 __attribute__((ext_vector_type(4)));
typedef short s16x8 __attribute__((ext_vector_type(8)));
typedef float f32x4 __attribute__((ext_vector_type(4)));

__device__ __forceinline__ short f2bf(float f) {
    unsigned u = __float_as_uint(f);
    unsigned r = (u + 0x7FFFu + ((u >> 16) & 1u)) >> 16;   // RNE to bf16
    return (short)r;
}

// ---------------- prep 1: Qb = bf16(Q*0.125), Wb = bf16(K+R) ----------------
__global__ __launch_bounds__(256) void prep_qw(
    const float4* __restrict__ Q, const float4* __restrict__ K,
    const float4* __restrict__ R, s16x4* __restrict__ Qb, s16x4* __restrict__ Wb)
{
    int i = blockIdx.x * 256 + threadIdx.x;     // 524288 float4 groups
    float4 q = Q[i];
    s16x4 qo;
    qo[0] = f2bf(q.x * 0.125f); qo[1] = f2bf(q.y * 0.125f);
    qo[2] = f2bf(q.z * 0.125f); qo[3] = f2bf(q.w * 0.125f);
    Qb[i] = qo;
    float4 k = K[i], r = R[i];
    s16x4 wo;
    wo[0] = f2bf(k.x + r.x); wo[1] = f2bf(k.y + r.y);
    wo[2] = f2bf(k.z + r.z); wo[3] = f2bf(k.w + r.w);
    Wb[i] = wo;
}

// ---------------- prep 2: Vt[b][d][m] = bf16(V[b][m][d]) ----------------
__global__ __launch_bounds__(256) void prep_vt(
    const float4* __restrict__ V, s16x4* __restrict__ Vt)
{
    __shared__ short T[64][72];                 // 64x64 tile, padded rows
    int b = blockIdx.y, m0 = blockIdx.x * 64;
    int t = threadIdx.x;
    #pragma unroll
    for (int j = 0; j < 4; ++j) {
        int p = j * 256 + t;                    // 0..1023 float4 slots
        int row = p >> 4;                       // m-local
        int c4  = p & 15;                       // d group of 4
        float4 v = V[(size_t)(b * SEQ + m0 + row) * (DH / 4) + c4];
        T[row][c4 * 4 + 0] = f2bf(v.x);
        T[row][c4 * 4 + 1] = f2bf(v.y);
        T[row][c4 * 4 + 2] = f2bf(v.z);
        T[row][c4 * 4 + 3] = f2bf(v.w);
    }
    __syncthreads();
    #pragma unroll
    for (int j = 0; j < 4; ++j) {
        int p = j * 256 + t;
        int d  = p >> 4;                        // 0..63
        int mc = p & 15;                        // m chunk of 4
        s16x4 o;
        o[0] = T[mc * 4 + 0][d];
        o[1] = T[mc * 4 + 1][d];
        o[2] = T[mc * 4 + 2][d];
        o[3] = T[mc * 4 + 3][d];
        Vt[(size_t)(b * DH + d) * (SEQ / 4) + (m0 / 4) + mc] = o;
    }
}

// ---------------- main: fused S-write + online-softmax + PV ----------------
// grid (16, 32), 256 threads. Wave w owns rows [bx*64 + 16w, +16) of batch b.
__global__ __launch_bounds__(256) void attn_main(
    const short* __restrict__ Qb, const short* __restrict__ Wb,
    const short* __restrict__ Vt, float* __restrict__ out,
    float* __restrict__ score)
{
    __shared__ short Ps[4][16 * 72];            // per-wave P staging, padded
    const int tid  = threadIdx.x;
    const int wave = tid >> 6;
    const int lane = tid & 63;
    const int l15  = lane & 15;
    const int quad = lane >> 4;
    const int b    = blockIdx.y;
    const int n0   = blockIdx.x * 64 + wave * 16;

    // Q A-fragments: rows n0+l15, k-steps 0 and 32 (16B contiguous each)
    const s16x8* Qv = (const s16x8*)(Qb + (size_t)(b * SEQ + n0 + l15) * DH + quad * 8);
    s16x8 aq0 = Qv[0];
    s16x8 aq1 = Qv[4];

    f32x4 oacc[4];
    float mrow[4], lrow[4];
    #pragma unroll
    for (int tc = 0; tc < 4; ++tc) { oacc[tc][0] = 0.f; oacc[tc][1] = 0.f; oacc[tc][2] = 0.f; oacc[tc][3] = 0.f; }
    #pragma unroll
    for (int r = 0; r < 4; ++r) { mrow[r] = -1e30f; lrow[r] = 0.f; }

    float* scoreB = score + (size_t)b * SEQ * SEQ;

    for (int mi = 0; mi < 16; ++mi) {
        const int m0 = mi * 64;

        // ---- S tile: 16 rows x 64 cols, S = (Q*scale) @ W^T ----
        f32x4 sacc[4];
        #pragma unroll
        for (int tc = 0; tc < 4; ++tc) { sacc[tc][0] = 0.f; sacc[tc][1] = 0.f; sacc[tc][2] = 0.f; sacc[tc][3] = 0.f; }
        #pragma unroll
        for (int tc = 0; tc < 4; ++tc) {
            const s16x8* Wv = (const s16x8*)(Wb + (size_t)(b * SEQ + m0 + tc * 16 + l15) * DH + quad * 8);
            sacc[tc] = __builtin_amdgcn_mfma_f32_16x16x32_bf16(aq0, Wv[0], sacc[tc], 0, 0, 0);
            sacc[tc] = __builtin_amdgcn_mfma_f32_16x16x32_bf16(aq1, Wv[4], sacc[tc], 0, 0, 0);
        }

        // ---- write raw scores (this IS output 1) ----
        #pragma unroll
        for (int tc = 0; tc < 4; ++tc)
            #pragma unroll
            for (int r = 0; r < 4; ++r)
                scoreB[(size_t)(n0 + quad * 4 + r) * SEQ + m0 + tc * 16 + l15] = sacc[tc][r];

        // ---- online softmax (wave-local; 16-lane shfl groups == one quad's rows) ----
        float mnew[4], alpha[4];
        #pragma unroll
        for (int r = 0; r < 4; ++r) {
            float mx = fmaxf(fmaxf(sacc[0][r], sacc[1][r]), fmaxf(sacc[2][r], sacc[3][r]));
            mx = fmaxf(mx, __shfl_xor(mx, 1));
            mx = fmaxf(mx, __shfl_xor(mx, 2));
            mx = fmaxf(mx, __shfl_xor(mx, 4));
            mx = fmaxf(mx, __shfl_xor(mx, 8));
            mnew[r]  = fmaxf(mrow[r], mx);
            alpha[r] = __expf(mrow[r] - mnew[r]);
            mrow[r]  = mnew[r];
        }
        float p[4][4];
        float rs[4] = {0.f, 0.f, 0.f, 0.f};
        #pragma unroll
        for (int tc = 0; tc < 4; ++tc)
            #pragma unroll
            for (int r = 0; r < 4; ++r) {
                p[tc][r] = __expf(sacc[tc][r] - mnew[r]);
                rs[r] += p[tc][r];
            }
        #pragma unroll
        for (int r = 0; r < 4; ++r) {
            rs[r] += __shfl_xor(rs[r], 1);
            rs[r] += __shfl_xor(rs[r], 2);
            rs[r] += __shfl_xor(rs[r], 4);
            rs[r] += __shfl_xor(rs[r], 8);
            lrow[r] = lrow[r] * alpha[r] + rs[r];
        }
        #pragma unroll
        for (int tc = 0; tc < 4; ++tc)
            #pragma unroll
            for (int r = 0; r < 4; ++r)
                oacc[tc][r] *= alpha[r];

        // ---- stage P (C-layout -> row-major bf16 in LDS) ----
        #pragma unroll
        for (int tc = 0; tc < 4; ++tc)
            #pragma unroll
            for (int r = 0; r < 4; ++r)
                Ps[wave][(quad * 4 + r) * 72 + tc * 16 + l15] = f2bf(p[tc][r]);
        __syncthreads();   // guarantee LDS write->read visibility (waves are uniform)

        // ---- PV: O += P @ V ----
        #pragma unroll
        for (int k0 = 0; k0 < 2; ++k0) {
            s16x8 pa = *(const s16x8*)&Ps[wave][l15 * 72 + k0 * 32 + quad * 8];
            #pragma unroll
            for (int tc = 0; tc < 4; ++tc) {
                const s16x8* Vv = (const s16x8*)(Vt + (size_t)(b * DH + tc * 16 + l15) * SEQ + m0 + k0 * 32 + quad * 8);
                oacc[tc] = __builtin_amdgcn_mfma_f32_16x16x32_bf16(pa, Vv[0], oacc[tc], 0, 0, 0);
            }
        }
        __syncthreads();   // protect Ps against next-iter overwrite ordering
    }

    // ---- epilogue: out = O / l ----
    #pragma unroll
    for (int tc = 0; tc < 4; ++tc)
        #pragma unroll
        for (int r = 0; r < 4; ++r)
            out[(size_t)(b * SEQ + n0 + quad * 4 + r) * DH + tc * 16 + l15] = oacc[tc][r] / lrow[r];
}

extern "C" void kernel_launch(void* const* d_in, const int* in_sizes, int n_in,
                              void* d_out, int out_size, void* d_ws, size_t ws_size,
                              hipStream_t stream) {
    const float* Q = (const float*)d_in[0];
    const float* K = (const float*)d_in[1];
    const float* V = (const float*)d_in[2];
    const float* R = (const float*)d_in[3];

    const size_t NEL = (size_t)BATCH * SEQ * DH;   // 2,097,152
    short* Qb = (short*)d_ws;
    short* Wb = Qb + NEL;
    short* Vt = Wb + NEL;

    float* out   = (float*)d_out;
    float* score = out + NEL;

    prep_qw<<<dim3(NEL / 4 / 256), dim3(256), 0, stream>>>(
        (const float4*)Q, (const float4*)K, (const float4*)R,
        (s16x4*)Qb, (s16x4*)Wb);
    prep_vt<<<dim3(SEQ / 64, BATCH), dim3(256), 0, stream>>>(
        (const float4*)V, (s16x4*)Vt);
    attn_main<<<dim3(SEQ / 64, BATCH), dim3(256), 0, stream>>>(
        Qb, Wb, Vt, out, score);
}